// Round 8
// baseline (61.817 us; speedup 1.0000x reference)
//
#include <hip/hip_runtime.h>

// Problem constants (B=4, N=2048 fixed by the reference setup)
#define BB 4
#define NN 2048
#define NPTS (BB * NN)                          // 8192 points
#define PSTR 20                                 // packed floats per point (5 x float4)
#define TS 256                                  // n-tile size
#define TT (NN / TS)                            // 8 tiles per batch
#define NPAIRS (TT * (TT + 1) / 2)              // 36 tri tile pairs (incl. diag)
#define MCH 16                                  // m-points staged per block
#define MSPL (TS / MCH)                         // 16 m-chunks per tile pair
#define JOBS_PER_B (NPAIRS * MSPL)              // 576
#define NJOBS (JOBS_PER_B * BB)                 // 2304 blocks
#define BLK 128                                 // 2 waves
#define ROWS 2                                  // rows {tid, tid+128}: no redundancy
// weight 2 for every surviving (m<n) pair folded into the final scale
#define SCALE (2.0f / ((float)BB * (float)NN * (float)NN))

// d_ws layout
#define WS_COUNTER_OFF 0
#define WS_PART_OFF    256
#define WS_PACK_OFF    (1 << 20)
#define WS_NEEDED      (WS_PACK_OFF + (size_t)NPTS * PSTR * 4)

__device__ __forceinline__ void quat_to_R(float qw, float qx, float qy, float qz, float* R) {
    R[0] = 1.f - 2.f * (qy * qy + qz * qz);
    R[1] = 2.f * (qx * qy - qz * qw);
    R[2] = 2.f * (qx * qz + qy * qw);
    R[3] = 2.f * (qx * qy + qz * qw);
    R[4] = 1.f - 2.f * (qx * qx + qz * qz);
    R[5] = 2.f * (qy * qz - qx * qw);
    R[6] = 2.f * (qx * qz - qy * qw);
    R[7] = 2.f * (qy * qz + qx * qw);
    R[8] = 1.f - 2.f * (qx * qx + qy * qy);
}

// Pack per-point: {x,y,z,sx | sy,sz,vx,vy | vz,R0,R1,R2 | R3,R4,R5,R6 | R7,R8,0,0}
__global__ __launch_bounds__(256) void pack_kernel(
    const float* __restrict__ xyz, const float* __restrict__ scales,
    const float* __restrict__ rot, const float* __restrict__ vel,
    float* __restrict__ pk)
{
    const int i = blockIdx.x * 256 + threadIdx.x;
    if (i >= NPTS) return;
    const size_t i3 = 3 * (size_t)i;
    const float4 q = *reinterpret_cast<const float4*>(rot + 4 * (size_t)i);
    float R[9];
    quat_to_R(q.x, q.y, q.z, q.w, R);
    float4* o = reinterpret_cast<float4*>(pk + PSTR * (size_t)i);
    o[0] = make_float4(xyz[i3], xyz[i3 + 1], xyz[i3 + 2], scales[i3]);
    o[1] = make_float4(scales[i3 + 1], scales[i3 + 2], vel[i3], vel[i3 + 1]);
    o[2] = make_float4(vel[i3 + 2], R[0], R[1], R[2]);
    o[3] = make_float4(R[3], R[4], R[5], R[6]);
    o[4] = make_float4(R[7], R[8], 0.f, 0.f);
}

// Lower-triangle (m<n) pair sum, weight 2 in SCALE.
// Block = (batch, tri tile-pair, m-chunk of 16). 128 threads, each owning rows
// {tid, tid+128} of the 256-row n-tile (no redundant prologue). m-side: 16
// points staged to LDS as 5xfloat4, read with wave-uniform broadcast addrs.
// Prologue is 10 float4 loads from the packed buffer (no quat math here).
__global__ __launch_bounds__(BLK) void pair_kernel(
    const float* __restrict__ pk,
    float* __restrict__ partials, unsigned int* __restrict__ counter,
    float* __restrict__ outp)
{
    __shared__ float4 sm[MCH][5];
    __shared__ float wsum[2];
    __shared__ int lastflag;

    const int tid = threadIdx.x;
    const int jid = blockIdx.x;
    const int b   = jid / JOBS_PER_B;
    const int rem = jid % JOBS_PER_B;
    const int p   = rem / MSPL;     // triangular tile-pair index
    const int mc  = rem % MSPL;     // m-chunk

    // decode p -> (ti >= tj)
    int ti = 0;
    while ((ti + 1) * (ti + 2) / 2 <= p) ++ti;
    const int tj = p - ti * (ti + 1) / 2;
    const bool diag = (ti == tj);

    const int n_base = ti * TS;
    const int m_blk  = tj * TS + mc * MCH;

    const float4* pkb = reinterpret_cast<const float4*>(pk) + (size_t)b * NN * 5;

    // ---- stage m-chunk (16 pts x 5 float4) : threads 0..79, one float4 each ----
    if (tid < MCH * 5) {
        const int j = tid / 5;
        const int c = tid - 5 * j;
        sm[j][c] = pkb[(size_t)(m_blk + j) * 5 + c];
    }

    // ---- own n-rows from packed buffer (2 rows x 5 float4) ----
    float px[ROWS], py[ROWS], pz[ROWS];
    float sx[ROWS], sy[ROWS], sz[ROWS];
    float vx[ROWS], vy[ROWS], vz[ROWS];
    float Rn[ROWS][9];
    int   nidx[ROWS];
    #pragma unroll
    for (int r = 0; r < ROWS; ++r) {
        const int n = n_base + tid + 128 * r;
        nidx[r] = n;
        const float4* np4 = pkb + (size_t)n * 5;
        const float4 n0 = np4[0], n1 = np4[1], n2 = np4[2], n3 = np4[3], n4 = np4[4];
        px[r] = n0.x; py[r] = n0.y; pz[r] = n0.z;
        sx[r] = n0.w; sy[r] = n1.x; sz[r] = n1.y;
        vx[r] = n1.z; vy[r] = n1.w; vz[r] = n2.x;
        Rn[r][0] = n2.y; Rn[r][1] = n2.z; Rn[r][2] = n2.w;
        Rn[r][3] = n3.x; Rn[r][4] = n3.y; Rn[r][5] = n3.z;
        Rn[r][6] = n3.w; Rn[r][7] = n4.x; Rn[r][8] = n4.y;
    }

    __syncthreads();

    float acc = 0.f;

    auto inner = [&](bool isDiag) {
        #pragma unroll 4
        for (int j = 0; j < MCH; ++j) {
            const int m = m_blk + j;
            const float4 c0 = sm[j][0];
            const float4 c1 = sm[j][1];
            const float4 c2 = sm[j][2];
            const float4 c3 = sm[j][3];
            const float4 c4 = sm[j][4];
            #pragma unroll
            for (int r = 0; r < ROWS; ++r) {
                const float dx = px[r] - c0.x, dy = py[r] - c0.y, dz = pz[r] - c0.z;
                const float d2 = fmaf(dx, dx, fmaf(dy, dy, fmaf(dz, dz, 1e-8f)));
                const float rinv = __builtin_amdgcn_rsqf(d2);
                // r_dir(n,m): (diff^T R_n) scaled by s_m
                const float a0 = fmaf(dx, Rn[r][0], fmaf(dy, Rn[r][3], dz * Rn[r][6])) * c0.w;
                const float a1 = fmaf(dx, Rn[r][1], fmaf(dy, Rn[r][4], dz * Rn[r][7])) * c1.x;
                const float a2 = fmaf(dx, Rn[r][2], fmaf(dy, Rn[r][5], dz * Rn[r][8])) * c1.y;
                const float qa = __builtin_amdgcn_sqrtf(fmaf(a0, a0, fmaf(a1, a1, a2 * a2)));
                // r_dir(m,n): (diff^T R_m) scaled by s_n (sign dies in the square)
                const float b0 = fmaf(dx, c2.y, fmaf(dy, c3.x, dz * c3.w)) * sx[r];
                const float b1 = fmaf(dx, c2.z, fmaf(dy, c3.y, dz * c4.x)) * sy[r];
                const float b2 = fmaf(dx, c2.w, fmaf(dy, c3.z, dz * c4.y)) * sz[r];
                const float qb = __builtin_amdgcn_sqrtf(fmaf(b0, b0, fmaf(b1, b1, b2 * b2)));
                // overlap = rinv * relu(qa + qb - d2)
                const float ww = fmaxf(qa + qb - d2, 0.f);
                const float ov = ww * rinv;
                const float rc = __builtin_amdgcn_rcpf(fmaf(0.1f, ov, 1.f));
                // v_approach = (v_n - v_m).diff * rinv ; ramp = relu(-v_approach)
                const float vdot = fmaf(vx[r] - c1.z, dx,
                                   fmaf(vy[r] - c1.w, dy, (vz[r] - c2.x) * dz));
                const float ramp = fmaxf(-vdot * rinv, 0.f);
                // t = spec + 0.1*ov*ramp = ov * (ov*rc + 0.1*ramp)
                float t = ov * fmaf(ov, rc, 0.1f * ramp);
                if (isDiag && !(m < nidx[r])) t = 0.f;   // diag tiles: keep m<n only
                acc += t;
            }
        }
    };
    if (diag) inner(true); else inner(false);

    // ---- block reduction (2 waves) ----
    #pragma unroll
    for (int off = 32; off > 0; off >>= 1)
        acc += __shfl_down(acc, off, 64);
    if ((tid & 63) == 0) wsum[tid >> 6] = acc;
    __syncthreads();

    if (tid == 0) {
        partials[jid] = wsum[0] + wsum[1];
        __threadfence();                               // release
        const unsigned int done = atomicAdd(counter, 1u);
        lastflag = (done == (unsigned int)(NJOBS - 1));
    }
    __syncthreads();

    if (lastflag) {
        __threadfence();                               // acquire
        const float4* p4 = reinterpret_cast<const float4*>(partials);
        float s = 0.f;
        for (int i = tid; i < NJOBS / 4; i += BLK) {
            const float4 v = p4[i];
            s += v.x + v.y + v.z + v.w;
        }
        #pragma unroll
        for (int off = 32; off > 0; off >>= 1)
            s += __shfl_down(s, off, 64);
        if ((tid & 63) == 0) wsum[tid >> 6] = s;
        __syncthreads();
        if (tid == 0) outp[0] = (wsum[0] + wsum[1]) * SCALE;
    }
}

// Safety fallback (never expected to run: needs no workspace). One thread per
// n-row, loops all m<n, per-wave reduce + atomicAdd.
__global__ __launch_bounds__(256) void naive_kernel(
    const float* __restrict__ xyz, const float* __restrict__ scales,
    const float* __restrict__ rot, const float* __restrict__ vel,
    float* __restrict__ outp)
{
    const int g = blockIdx.x * 256 + threadIdx.x;   // 8192 threads
    const int b = g / NN, n = g % NN;
    const size_t i3 = ((size_t)b * NN + n) * 3;
    const float4 qn = *reinterpret_cast<const float4*>(rot + ((size_t)b * NN + n) * 4);
    float Rn[9];
    quat_to_R(qn.x, qn.y, qn.z, qn.w, Rn);
    const float px = xyz[i3], py = xyz[i3+1], pz = xyz[i3+2];
    const float sx = scales[i3], sy = scales[i3+1], sz = scales[i3+2];
    const float vx = vel[i3], vy = vel[i3+1], vz = vel[i3+2];
    float acc = 0.f;
    for (int m = 0; m < n; ++m) {
        const size_t j3 = ((size_t)b * NN + m) * 3;
        const float4 qm = *reinterpret_cast<const float4*>(rot + ((size_t)b * NN + m) * 4);
        float Rm[9];
        quat_to_R(qm.x, qm.y, qm.z, qm.w, Rm);
        const float dx = px - xyz[j3], dy = py - xyz[j3+1], dz = pz - xyz[j3+2];
        const float d2 = fmaf(dx, dx, fmaf(dy, dy, fmaf(dz, dz, 1e-8f)));
        const float rinv = __builtin_amdgcn_rsqf(d2);
        const float a0 = fmaf(dx, Rn[0], fmaf(dy, Rn[3], dz*Rn[6])) * scales[j3];
        const float a1 = fmaf(dx, Rn[1], fmaf(dy, Rn[4], dz*Rn[7])) * scales[j3+1];
        const float a2 = fmaf(dx, Rn[2], fmaf(dy, Rn[5], dz*Rn[8])) * scales[j3+2];
        const float qa = __builtin_amdgcn_sqrtf(fmaf(a0,a0,fmaf(a1,a1,a2*a2)));
        const float b0 = fmaf(dx, Rm[0], fmaf(dy, Rm[3], dz*Rm[6])) * sx;
        const float b1 = fmaf(dx, Rm[1], fmaf(dy, Rm[4], dz*Rm[7])) * sy;
        const float b2 = fmaf(dx, Rm[2], fmaf(dy, Rm[5], dz*Rm[8])) * sz;
        const float qb = __builtin_amdgcn_sqrtf(fmaf(b0,b0,fmaf(b1,b1,b2*b2)));
        const float ww = fmaxf(qa + qb - d2, 0.f);
        const float ov = ww * rinv;
        const float rc = __builtin_amdgcn_rcpf(fmaf(0.1f, ov, 1.f));
        const float vdot = fmaf(vx - vel[j3], dx, fmaf(vy - vel[j3+1], dy, (vz - vel[j3+2]) * dz));
        const float ramp = fmaxf(-vdot * rinv, 0.f);
        acc += ov * fmaf(ov, rc, 0.1f * ramp);
    }
    #pragma unroll
    for (int off = 32; off > 0; off >>= 1)
        acc += __shfl_down(acc, off, 64);
    if ((threadIdx.x & 63) == 0) atomicAdd(outp, acc * SCALE);
}

extern "C" void kernel_launch(void* const* d_in, const int* in_sizes, int n_in,
                              void* d_out, int out_size, void* d_ws, size_t ws_size,
                              hipStream_t stream)
{
    const float* xyz    = (const float*)d_in[0];
    const float* scales = (const float*)d_in[1];
    const float* rot    = (const float*)d_in[2];
    const float* vel    = (const float*)d_in[3];
    float* out = (float*)d_out;

    if (ws_size >= WS_NEEDED) {
        unsigned int* counter = (unsigned int*)((char*)d_ws + WS_COUNTER_OFF);
        float* partials       = (float*)((char*)d_ws + WS_PART_OFF);
        float* pk             = (float*)((char*)d_ws + WS_PACK_OFF);
        hipMemsetAsync(counter, 0, sizeof(unsigned int), stream);   // graph-safe
        pack_kernel<<<(NPTS + 255) / 256, 256, 0, stream>>>(xyz, scales, rot, vel, pk);
        pair_kernel<<<NJOBS, BLK, 0, stream>>>(pk, partials, counter, out);
    } else {
        hipMemsetAsync(d_out, 0, sizeof(float), stream);
        naive_kernel<<<NPTS / 256, 256, 0, stream>>>(xyz, scales, rot, vel, out);
    }
}

// Round 9
// 37.847 us; speedup vs baseline: 1.6334x; 1.6334x over previous
//
#include <hip/hip_runtime.h>

// Problem constants (B=4, N=2048 fixed by the reference setup)
#define BB 4
#define NN 2048
#define NPTS (BB * NN)                          // 8192 points
#define TILE 512                                // n-tile rows
#define TT (NN / TILE)                          // 4 tiles per batch
#define NTP (TT * (TT + 1) / 2)                 // 10 tri tile pairs (incl diag)
#define MS 32                                   // m-points staged per block
#define MSPL (TILE / MS)                        // 16 m-slices per tile pair
#define JPB (NTP * MSPL)                        // 160 jobs per batch
#define NJOBS (JPB * BB)                        // 640 blocks
#define BLK 256                                 // 4 waves
#define ROWS 2                                  // rows {tid, tid+256} per thread
// weight 2 for every surviving (m<n) pair folded into the final scale
#define SCALE (2.0f / ((float)BB * (float)NN * (float)NN))

// d_ws layout: counter @0, partials @256, SoA packed arrays @1MB
#define WS_COUNTER_OFF 0
#define WS_PART_OFF    256
#define WS_PACK_OFF    (1 << 20)
#define WS_NEEDED      (WS_PACK_OFF + (size_t)NPTS * 5 * 16)

__device__ __forceinline__ void quat_to_R(float qw, float qx, float qy, float qz, float* R) {
    R[0] = 1.f - 2.f * (qy * qy + qz * qz);
    R[1] = 2.f * (qx * qy - qz * qw);
    R[2] = 2.f * (qx * qz + qy * qw);
    R[3] = 2.f * (qx * qy + qz * qw);
    R[4] = 1.f - 2.f * (qx * qx + qz * qz);
    R[5] = 2.f * (qy * qz - qx * qw);
    R[6] = 2.f * (qx * qz - qy * qw);
    R[7] = 2.f * (qy * qz + qx * qw);
    R[8] = 1.f - 2.f * (qx * qx + qy * qy);
}

// SoA pack: 5 float4 arrays of NPTS entries each.
// A0={x,y,z,sx} A1={sy,sz,vx,vy} A2={vz,R0,R1,R2} A3={R3,R4,R5,R6} A4={R7,R8,0,0}
__global__ __launch_bounds__(256) void pack_kernel(
    const float* __restrict__ xyz, const float* __restrict__ scales,
    const float* __restrict__ rot, const float* __restrict__ vel,
    float4* __restrict__ pk)
{
    const int i = blockIdx.x * 256 + threadIdx.x;
    if (i >= NPTS) return;
    const size_t i3 = 3 * (size_t)i;
    const float4 q = *reinterpret_cast<const float4*>(rot + 4 * (size_t)i);
    float R[9];
    quat_to_R(q.x, q.y, q.z, q.w, R);
    pk[0 * NPTS + i] = make_float4(xyz[i3], xyz[i3 + 1], xyz[i3 + 2], scales[i3]);
    pk[1 * NPTS + i] = make_float4(scales[i3 + 1], scales[i3 + 2], vel[i3], vel[i3 + 1]);
    pk[2 * NPTS + i] = make_float4(vel[i3 + 2], R[0], R[1], R[2]);
    pk[3 * NPTS + i] = make_float4(R[3], R[4], R[5], R[6]);
    pk[4 * NPTS + i] = make_float4(R[7], R[8], 0.f, 0.f);
}

// Lower-triangle (m<n) pair sum, weight 2 in SCALE.
// Block = (batch, tri 512-tile-pair, 32-m-slice). 256 threads x ROWS=2 rows
// {tid, tid+256} cover the 512-row n-tile. 32 m-points staged to LDS; inner
// loop reads 5 uniform float4 broadcasts per m (conflict-free) + registers.
// Long loop (32 j x 2 rows = 64 pairs/thread), 2.5 blocks/CU, 5 chains/SIMD.
__global__ __launch_bounds__(BLK) void pair_kernel(
    const float4* __restrict__ pk,
    float* __restrict__ partials, unsigned int* __restrict__ counter,
    float* __restrict__ outp)
{
    __shared__ float4 sm[MS][5];
    __shared__ float wsum[4];
    __shared__ int lastflag;

    const int tid = threadIdx.x;
    const int jid = blockIdx.x;
    const int b   = jid / JPB;
    const int rem = jid % JPB;
    const int p   = rem / MSPL;     // triangular tile-pair index (0..9)
    const int sl  = rem % MSPL;     // m-slice

    // decode p -> (ti >= tj)
    int ti = 0;
    while ((ti + 1) * (ti + 2) / 2 <= p) ++ti;
    const int tj = p - ti * (ti + 1) / 2;
    const bool diag = (ti == tj);

    const int n0 = ti * TILE;
    const int m0 = tj * TILE + sl * MS;
    const int gb = b * NN;

    // ---- stage m-slice (32 pts x 5 float4), coalesced per array ----
    if (tid < MS) {
        const int gi = gb + m0 + tid;
        sm[tid][0] = pk[0 * NPTS + gi];
        sm[tid][1] = pk[1 * NPTS + gi];
        sm[tid][2] = pk[2 * NPTS + gi];
        sm[tid][3] = pk[3 * NPTS + gi];
        sm[tid][4] = pk[4 * NPTS + gi];
    }

    // ---- own n-rows (2 per thread), coalesced per array ----
    float px[ROWS], py[ROWS], pz[ROWS];
    float sx[ROWS], sy[ROWS], sz[ROWS];
    float vx[ROWS], vy[ROWS], vz[ROWS];
    float Rn[ROWS][9];
    int   nidx[ROWS];
    #pragma unroll
    for (int r = 0; r < ROWS; ++r) {
        const int n  = n0 + tid + 256 * r;
        nidx[r] = n;
        const int gi = gb + n;
        const float4 n0v = pk[0 * NPTS + gi];
        const float4 n1v = pk[1 * NPTS + gi];
        const float4 n2v = pk[2 * NPTS + gi];
        const float4 n3v = pk[3 * NPTS + gi];
        const float4 n4v = pk[4 * NPTS + gi];
        px[r] = n0v.x; py[r] = n0v.y; pz[r] = n0v.z;
        sx[r] = n0v.w; sy[r] = n1v.x; sz[r] = n1v.y;
        vx[r] = n1v.z; vy[r] = n1v.w; vz[r] = n2v.x;
        Rn[r][0] = n2v.y; Rn[r][1] = n2v.z; Rn[r][2] = n2v.w;
        Rn[r][3] = n3v.x; Rn[r][4] = n3v.y; Rn[r][5] = n3v.z;
        Rn[r][6] = n3v.w; Rn[r][7] = n4v.x; Rn[r][8] = n4v.y;
    }

    __syncthreads();

    float acc = 0.f;

    auto inner = [&](bool isDiag) {
        #pragma unroll 4
        for (int j = 0; j < MS; ++j) {
            const int m = m0 + j;                 // uniform
            const float4 c0 = sm[j][0];
            const float4 c1 = sm[j][1];
            const float4 c2 = sm[j][2];
            const float4 c3 = sm[j][3];
            const float4 c4 = sm[j][4];
            #pragma unroll
            for (int r = 0; r < ROWS; ++r) {
                const float dx = px[r] - c0.x, dy = py[r] - c0.y, dz = pz[r] - c0.z;
                const float d2 = fmaf(dx, dx, fmaf(dy, dy, fmaf(dz, dz, 1e-8f)));
                const float rinv = __builtin_amdgcn_rsqf(d2);
                // r_dir(n,m): (diff^T R_n) scaled by s_m
                const float a0 = fmaf(dx, Rn[r][0], fmaf(dy, Rn[r][3], dz * Rn[r][6])) * c0.w;
                const float a1 = fmaf(dx, Rn[r][1], fmaf(dy, Rn[r][4], dz * Rn[r][7])) * c1.x;
                const float a2 = fmaf(dx, Rn[r][2], fmaf(dy, Rn[r][5], dz * Rn[r][8])) * c1.y;
                const float qa = __builtin_amdgcn_sqrtf(fmaf(a0, a0, fmaf(a1, a1, a2 * a2)));
                // r_dir(m,n): (diff^T R_m) scaled by s_n (sign dies in the square)
                const float b0 = fmaf(dx, c2.y, fmaf(dy, c3.x, dz * c3.w)) * sx[r];
                const float b1 = fmaf(dx, c2.z, fmaf(dy, c3.y, dz * c4.x)) * sy[r];
                const float b2 = fmaf(dx, c2.w, fmaf(dy, c3.z, dz * c4.y)) * sz[r];
                const float qb = __builtin_amdgcn_sqrtf(fmaf(b0, b0, fmaf(b1, b1, b2 * b2)));
                // overlap = rinv * relu(qa + qb - d2)
                const float ww = fmaxf(qa + qb - d2, 0.f);
                const float ov = ww * rinv;
                const float rc = __builtin_amdgcn_rcpf(fmaf(0.1f, ov, 1.f));
                // v_approach = (v_n - v_m).diff * rinv ; ramp = relu(-v_approach)
                const float vdot = fmaf(vx[r] - c1.z, dx,
                                   fmaf(vy[r] - c1.w, dy, (vz[r] - c2.x) * dz));
                const float ramp = fmaxf(-vdot * rinv, 0.f);
                // t = spec + 0.1*ov*ramp = ov * (ov*rc + 0.1*ramp)
                float t = ov * fmaf(ov, rc, 0.1f * ramp);
                if (isDiag && !(m < nidx[r])) t = 0.f;   // diag tiles: keep m<n only
                acc += t;
            }
        }
    };
    if (diag) inner(true); else inner(false);

    // ---- block reduction (4 waves) ----
    #pragma unroll
    for (int off = 32; off > 0; off >>= 1)
        acc += __shfl_down(acc, off, 64);
    if ((tid & 63) == 0) wsum[tid >> 6] = acc;
    __syncthreads();

    if (tid == 0) {
        partials[jid] = wsum[0] + wsum[1] + wsum[2] + wsum[3];
        __threadfence();                               // release
        const unsigned int done = atomicAdd(counter, 1u);
        lastflag = (done == (unsigned int)(NJOBS - 1));
    }
    __syncthreads();

    if (lastflag) {
        __threadfence();                               // acquire
        const float4* p4 = reinterpret_cast<const float4*>(partials);
        float s = 0.f;
        for (int i = tid; i < NJOBS / 4; i += BLK) {
            const float4 v = p4[i];
            s += v.x + v.y + v.z + v.w;
        }
        #pragma unroll
        for (int off = 32; off > 0; off >>= 1)
            s += __shfl_down(s, off, 64);
        if ((tid & 63) == 0) wsum[tid >> 6] = s;
        __syncthreads();
        if (tid == 0) outp[0] = (wsum[0] + wsum[1] + wsum[2] + wsum[3]) * SCALE;
    }
}

// Safety fallback (tiny workspace): one thread per n-row, loops m<n, atomic.
__global__ __launch_bounds__(256) void naive_kernel(
    const float* __restrict__ xyz, const float* __restrict__ scales,
    const float* __restrict__ rot, const float* __restrict__ vel,
    float* __restrict__ outp)
{
    const int g = blockIdx.x * 256 + threadIdx.x;   // 8192 threads
    const int b = g / NN, n = g % NN;
    const size_t i3 = ((size_t)b * NN + n) * 3;
    const float4 qn = *reinterpret_cast<const float4*>(rot + ((size_t)b * NN + n) * 4);
    float Rn[9];
    quat_to_R(qn.x, qn.y, qn.z, qn.w, Rn);
    const float px = xyz[i3], py = xyz[i3+1], pz = xyz[i3+2];
    const float sx = scales[i3], sy = scales[i3+1], sz = scales[i3+2];
    const float vx = vel[i3], vy = vel[i3+1], vz = vel[i3+2];
    float acc = 0.f;
    for (int m = 0; m < n; ++m) {
        const size_t j3 = ((size_t)b * NN + m) * 3;
        const float4 qm = *reinterpret_cast<const float4*>(rot + ((size_t)b * NN + m) * 4);
        float Rm[9];
        quat_to_R(qm.x, qm.y, qm.z, qm.w, Rm);
        const float dx = px - xyz[j3], dy = py - xyz[j3+1], dz = pz - xyz[j3+2];
        const float d2 = fmaf(dx, dx, fmaf(dy, dy, fmaf(dz, dz, 1e-8f)));
        const float rinv = __builtin_amdgcn_rsqf(d2);
        const float a0 = fmaf(dx, Rn[0], fmaf(dy, Rn[3], dz*Rn[6])) * scales[j3];
        const float a1 = fmaf(dx, Rn[1], fmaf(dy, Rn[4], dz*Rn[7])) * scales[j3+1];
        const float a2 = fmaf(dx, Rn[2], fmaf(dy, Rn[5], dz*Rn[8])) * scales[j3+2];
        const float qa = __builtin_amdgcn_sqrtf(fmaf(a0,a0,fmaf(a1,a1,a2*a2)));
        const float b0 = fmaf(dx, Rm[0], fmaf(dy, Rm[3], dz*Rm[6])) * sx;
        const float b1 = fmaf(dx, Rm[1], fmaf(dy, Rm[4], dz*Rm[7])) * sy;
        const float b2 = fmaf(dx, Rm[2], fmaf(dy, Rm[5], dz*Rm[8])) * sz;
        const float qb = __builtin_amdgcn_sqrtf(fmaf(b0,b0,fmaf(b1,b1,b2*b2)));
        const float ww = fmaxf(qa + qb - d2, 0.f);
        const float ov = ww * rinv;
        const float rc = __builtin_amdgcn_rcpf(fmaf(0.1f, ov, 1.f));
        const float vdot = fmaf(vx - vel[j3], dx, fmaf(vy - vel[j3+1], dy, (vz - vel[j3+2]) * dz));
        const float ramp = fmaxf(-vdot * rinv, 0.f);
        acc += ov * fmaf(ov, rc, 0.1f * ramp);
    }
    #pragma unroll
    for (int off = 32; off > 0; off >>= 1)
        acc += __shfl_down(acc, off, 64);
    if ((threadIdx.x & 63) == 0) atomicAdd(outp, acc * SCALE);
}

extern "C" void kernel_launch(void* const* d_in, const int* in_sizes, int n_in,
                              void* d_out, int out_size, void* d_ws, size_t ws_size,
                              hipStream_t stream)
{
    const float* xyz    = (const float*)d_in[0];
    const float* scales = (const float*)d_in[1];
    const float* rot    = (const float*)d_in[2];
    const float* vel    = (const float*)d_in[3];
    float* out = (float*)d_out;

    if (ws_size >= WS_NEEDED) {
        unsigned int* counter = (unsigned int*)((char*)d_ws + WS_COUNTER_OFF);
        float* partials       = (float*)((char*)d_ws + WS_PART_OFF);
        float4* pk            = (float4*)((char*)d_ws + WS_PACK_OFF);
        hipMemsetAsync(counter, 0, sizeof(unsigned int), stream);   // graph-safe
        pack_kernel<<<(NPTS + 255) / 256, 256, 0, stream>>>(xyz, scales, rot, vel, pk);
        pair_kernel<<<NJOBS, BLK, 0, stream>>>(pk, partials, counter, out);
    } else {
        hipMemsetAsync(d_out, 0, sizeof(float), stream);
        naive_kernel<<<NPTS / 256, 256, 0, stream>>>(xyz, scales, rot, vel, out);
    }
}